// Round 3
// baseline (105.151 us; speedup 1.0000x reference)
//
#include <hip/hip_runtime.h>

#define TGT 100
#define SRC 100
#define KDIM 512
#define HH 256
#define ROWS 1600              // BS*100
#define LOG2E2 2.8853900817779268f   // 2/ln(2): e^(2x) = 2^(LOG2E2*x)

typedef __attribute__((ext_vector_type(8))) short bf16x8;
typedef __attribute__((ext_vector_type(4))) float f32x4;

static __device__ __forceinline__ unsigned short f2b(float f) {
    union { float f; unsigned u; } v; v.f = f;
    unsigned r = (v.u + 0x7FFFu + ((v.u >> 16) & 1u)) >> 16;
    return (unsigned short)r;
}

// ---------------------------------------------------------------------------
// Kernel 1: fp32 inputs -> bf16 fragments -> MFMA GEMMs, fused exp2 epilogue.
//   row-tiles 0..99   : Ek [s_glob][h] = exp2(L * (keys @ Wk))        (fp32)
//   row-tiles 100..199: EqT[h][bt]     = exp2(L * (query @ Wq + b1))  (fp32, transposed)
// 1 wave per 16x16 C-tile; grid = 200 row-tiles x 16 h-tiles = 3200 blocks.
// MFMA 16x16x32 bf16: A[m=lane&15][k=quad*8+j], B[k=quad*8+j][n=lane&15],
// D: col=lane&15, row=quad*4+reg  (m89/m92/m120-verified layouts).
// ---------------------------------------------------------------------------
__global__ __launch_bounds__(64) void gemm_exp_kernel(
    const float* __restrict__ query,
    const float* __restrict__ keys,
    const float* __restrict__ Wk,
    const float* __restrict__ Wq,
    const float* __restrict__ b1,
    float* __restrict__ Ek, float* __restrict__ EqT)
{
    const int lane = threadIdx.x & 63;
    const int m = lane & 15, q = lane >> 4;
    const int bx = blockIdx.x;
    const int rt = bx >> 4;              // row tile 0..199
    const int h0 = (bx & 15) << 4;       // h tile base
    const bool isq = rt >= 100;
    const float* A = isq ? query : keys;
    const float* W = isq ? Wq : Wk;
    const int r0 = (isq ? rt - 100 : rt) << 4;
    const float* arow = A + (size_t)(r0 + m) * KDIM;

    f32x4 acc = {0.f, 0.f, 0.f, 0.f};
    for (int kk = 0; kk < 16; ++kk) {
        const int kb = kk * 32 + q * 8;              // this lane's 8 k's
        f32x4 a0 = *(const f32x4*)(arow + kb);       // 16B-aligned
        f32x4 a1 = *(const f32x4*)(arow + kb + 4);
        bf16x8 afrag, bfrag;
        #pragma unroll
        for (int j = 0; j < 4; ++j) { afrag[j] = (short)f2b(a0[j]); afrag[j+4] = (short)f2b(a1[j]); }
        const float* wp = W + (size_t)kb * HH + h0 + m;
        #pragma unroll
        for (int j = 0; j < 8; ++j) bfrag[j] = (short)f2b(wp[j * HH]);
        acc = __builtin_amdgcn_mfma_f32_16x16x32_bf16(afrag, bfrag, acc, 0, 0, 0);
    }

    const int hc = h0 + m;   // D col = lane&15 -> h index
    if (!isq) {
        #pragma unroll
        for (int r = 0; r < 4; ++r) {
            const int row = r0 + q * 4 + r;          // s_glob = b*100+s
            Ek[(size_t)row * HH + hc] = __builtin_amdgcn_exp2f(LOG2E2 * acc[r]);
        }
    } else {
        const float bb = b1[hc];
        #pragma unroll
        for (int r = 0; r < 4; ++r) {
            const int row = r0 + q * 4 + r;          // bt = b*100+t
            EqT[(size_t)hc * ROWS + row] =
                __builtin_amdgcn_exp2f(LOG2E2 * (acc[r] + bb));
        }
    }
}

// ---------------------------------------------------------------------------
// Kernel 2: score[b][s][t] = tanh( sumW2 - 2*sum_h W2[h]/(Ek[s,h]*Eq[t,h]+1) + b2 )
// One wave handles (b, s-pair, 64-t-chunk). s is wave-uniform -> Ek/W2 via the
// scalar path; EqT reads are lane-coalesced b32. No LDS. Output fp32.
// grid = 16 b * 50 s-pairs * 2 t-chunks = 1600 one-wave blocks.
// ---------------------------------------------------------------------------
__global__ __launch_bounds__(64) void score_kernel(
    const float* __restrict__ Ek, const float* __restrict__ EqT,
    const float* __restrict__ W2, const float* __restrict__ B2,
    float* __restrict__ out)
{
    const int lane = threadIdx.x & 63;
    const int bx = blockIdx.x;           // 0..1599
    const int tc = (bx & 1) << 6;        // 0 or 64
    const int g  = bx >> 1;              // 0..799
    const int sp = g % 50;
    const int b  = g / 50;
    const int s0 = sp * 2;
    const int t  = tc + lane;
    const int tcl = t < TGT ? t : TGT - 1;

    const float* __restrict__ ek0 = Ek + (size_t)(b * SRC + s0) * HH;
    const float* __restrict__ ek1 = ek0 + HH;
    const float* __restrict__ eq  = EqT + (size_t)b * TGT + tcl;

    float acc0 = 0.f, acc1 = 0.f;
    #pragma unroll 4
    for (int hp = 0; hp < HH / 2; ++hp) {
        const int h = hp * 2;
        const float w0 = W2[h], w1 = W2[h + 1];          // wave-uniform -> s_load
        const float e0 = eq[(size_t)h * ROWS];
        const float e1 = eq[(size_t)(h + 1) * ROWS];
        const float ka0 = ek0[h], ka1 = ek0[h + 1];      // wave-uniform -> s_load
        const float kb0 = ek1[h], kb1 = ek1[h + 1];
        acc0 = fmaf(w0, __builtin_amdgcn_rcpf(fmaf(ka0, e0, 1.0f)), acc0);
        acc1 = fmaf(w0, __builtin_amdgcn_rcpf(fmaf(kb0, e0, 1.0f)), acc1);
        acc0 = fmaf(w1, __builtin_amdgcn_rcpf(fmaf(ka1, e1, 1.0f)), acc0);
        acc1 = fmaf(w1, __builtin_amdgcn_rcpf(fmaf(kb1, e1, 1.0f)), acc1);
    }

    // sumW2 (wave allreduce over 256 fp32)
    float sw = W2[lane] + W2[lane + 64] + W2[lane + 128] + W2[lane + 192];
    #pragma unroll
    for (int off = 32; off; off >>= 1) sw += __shfl_xor(sw, off, 64);
    const float bias = B2[0];

    if (t < TGT) {
        float* o = out + ((size_t)b * SRC + s0) * TGT + t;
        const float x0 = sw - 2.f * acc0 + bias;
        const float g0 = __builtin_amdgcn_exp2f(LOG2E2 * x0);
        o[0]   = 1.f - 2.f * __builtin_amdgcn_rcpf(g0 + 1.f);
        const float x1 = sw - 2.f * acc1 + bias;
        const float g1 = __builtin_amdgcn_exp2f(LOG2E2 * x1);
        o[TGT] = 1.f - 2.f * __builtin_amdgcn_rcpf(g1 + 1.f);
    }
}

extern "C" void kernel_launch(void* const* d_in, const int* in_sizes, int n_in,
                              void* d_out, int out_size, void* d_ws, size_t ws_size,
                              hipStream_t stream) {
    const float* query = (const float*)d_in[0];
    const float* keys  = (const float*)d_in[1];
    const float* Wk    = (const float*)d_in[2];
    const float* Wq    = (const float*)d_in[3];
    const float* b1    = (const float*)d_in[4];
    const float* W2    = (const float*)d_in[5];
    const float* B2    = (const float*)d_in[6];
    float* out = (float*)d_out;

    float* Ek  = (float*)d_ws;                 // 1600*256 fp32
    float* EqT = Ek + (size_t)ROWS * HH;       // 256*1600 fp32 (transposed)

    gemm_exp_kernel<<<3200, 64, 0, stream>>>(query, keys, Wk, Wq, b1, Ek, EqT);
    score_kernel<<<1600, 64, 0, stream>>>(Ek, EqT, W2, B2, out);
}

// Round 4
// 93.770 us; speedup vs baseline: 1.1214x; 1.1214x over previous
//
#include <hip/hip_runtime.h>

#define TGT 100
#define SRC 100
#define KDIM 512
#define HH 256
#define ROWS 1600              // BS*100
#define LOG2E2 2.8853900817779268f   // 2/ln(2): e^(2x) = 2^(LOG2E2*x)

typedef __attribute__((ext_vector_type(8))) short bf16x8;
typedef __attribute__((ext_vector_type(4))) float f32x4;

// ws layout: floats [Ek 409600][EqT 409600] then shorts [Apk 1638400][Bpk 262144]
#define EQT_OFF 409600
#define PK_FLOAT_OFF 819200
#define APK_SHORTS 1638400     // 2 mats * 100 rt * 16 kk * 64 lane * 8

static __device__ __forceinline__ short f2b(float f) {
    union { float f; unsigned u; } v; v.f = f;
    return (short)((v.u + 0x7FFFu + ((v.u >> 16) & 1u)) >> 16);
}

// ---------------------------------------------------------------------------
// Prep: one-shot fp32->bf16 conversion into MFMA-fragment-contiguous layouts.
// Apk[(mat*100+rt)*16+kk][lane][8] : A[m=lane&15][k=kk*32+(lane>>4)*8+j]
// Bpk[(mat*16+ht)*16+kk][lane][8]  : W[k=kk*32+(lane>>4)*8+j][ht*16+(lane&15)]
// Pays the strided W gather + cvt ONCE (kernel-1 used to redo it per row-tile).
// ---------------------------------------------------------------------------
__global__ __launch_bounds__(256) void prep_kernel(
    const float* __restrict__ query, const float* __restrict__ keys,
    const float* __restrict__ Wk, const float* __restrict__ Wq,
    short* __restrict__ Apk, short* __restrict__ Bpk)
{
    const int tid = blockIdx.x * 256 + threadIdx.x;
    if (tid < 204800) {                       // A-pack: (mat,rt,kk,lane)
        const int lane = tid & 63;
        const int rest = tid >> 6;            // (mat*100+rt)*16 + kk
        const int kk = rest & 15;
        const int rg = rest >> 4;             // mat*100+rt, 0..199
        const float* A = (rg >= 100) ? query : keys;
        const int r = (rg % 100) * 16 + (lane & 15);
        const int kb = kk * 32 + (lane >> 4) * 8;
        const float* src = A + (size_t)r * KDIM + kb;
        f32x4 a0 = *(const f32x4*)src;
        f32x4 a1 = *(const f32x4*)(src + 4);
        bf16x8 v;
        #pragma unroll
        for (int j = 0; j < 4; ++j) { v[j] = f2b(a0[j]); v[j + 4] = f2b(a1[j]); }
        *(bf16x8*)(Apk + (size_t)tid * 8) = v;
    } else if (tid < 237568) {                // B-pack: (mat,ht,kk,lane)
        const int t2 = tid - 204800;
        const int lane = t2 & 63;
        const int rest = t2 >> 6;             // (mat*16+ht)*16 + kk
        const int kk = rest & 15;
        const int ht = (rest >> 4) & 15;
        const float* W = (rest >> 8) ? Wq : Wk;
        const int kb = kk * 32 + (lane >> 4) * 8;
        const int col = ht * 16 + (lane & 15);
        const float* wp = W + (size_t)kb * HH + col;
        bf16x8 v;
        #pragma unroll
        for (int j = 0; j < 8; ++j) v[j] = f2b(wp[(size_t)j * HH]);
        *(bf16x8*)(Bpk + (size_t)t2 * 8) = v;
    }
}

// ---------------------------------------------------------------------------
// GEMM+exp: 1 wave per 16x16 C-tile, 4 waves/block. Inner loop = 2 contiguous
// 1KB bf16x8 wave-loads + 1 MFMA (L2-BW bound).
//   rt 0..99  : Ek [b*100+s][h]  = exp2(L * keys@Wk)
//   rt 100..199: EqT[h][b*100+t] = exp2(L * (query@Wq + b1))  (transposed)
// D layout: col=lane&15, row=(lane>>4)*4+reg  (m89/m92-verified).
// ---------------------------------------------------------------------------
__global__ __launch_bounds__(256) void gemm_exp_kernel(
    const short* __restrict__ Apk, const short* __restrict__ Bpk,
    const float* __restrict__ b1,
    float* __restrict__ Ek, float* __restrict__ EqT)
{
    const int lane = threadIdx.x & 63;
    const int w = blockIdx.x * 4 + (threadIdx.x >> 6);   // 0..3199
    const int rt = w >> 4;               // 0..199 == mat*100 + rtl
    const int ht = w & 15;
    const int isq = rt >= 100;
    const short* ap = Apk + ((size_t)(rt * 16) * 64 + lane) * 8;
    const short* bp = Bpk + ((size_t)((isq * 16 + ht) * 16) * 64 + lane) * 8;

    f32x4 acc = {0.f, 0.f, 0.f, 0.f};
    #pragma unroll
    for (int kk = 0; kk < 16; ++kk) {
        bf16x8 af = *(const bf16x8*)(ap + (size_t)kk * 512);
        bf16x8 bf = *(const bf16x8*)(bp + (size_t)kk * 512);
        acc = __builtin_amdgcn_mfma_f32_16x16x32_bf16(af, bf, acc, 0, 0, 0);
    }

    const int m = lane & 15, q = lane >> 4;
    const int hc = ht * 16 + m;
    const int r0 = (isq ? rt - 100 : rt) * 16;
    if (!isq) {
        #pragma unroll
        for (int r = 0; r < 4; ++r) {
            const int row = r0 + q * 4 + r;
            Ek[(size_t)row * HH + hc] = __builtin_amdgcn_exp2f(LOG2E2 * acc[r]);
        }
    } else {
        const float bb = b1[hc];
        #pragma unroll
        for (int r = 0; r < 4; ++r) {
            const int row = r0 + q * 4 + r;
            EqT[(size_t)hc * ROWS + row] =
                __builtin_amdgcn_exp2f(LOG2E2 * (acc[r] + bb));
        }
    }
}

// ---------------------------------------------------------------------------
// Score: score[b][s][t] = tanh(sumW2 - 2*sum_h W2[h]/(Ek[s,h]*Eq[t,h]+1) + b2)
// Block (256 thr) = (b, s-pair, 64-t-chunk); each of 4 waves takes a 64-h
// quarter (25 waves/CU for latency hiding), 2KB LDS reduce, waves 0/1 store.
// ---------------------------------------------------------------------------
__global__ __launch_bounds__(256) void score_kernel(
    const float* __restrict__ Ek, const float* __restrict__ EqT,
    const float* __restrict__ W2, const float* __restrict__ B2,
    float* __restrict__ out)
{
    __shared__ float red[2][4][64];
    const int lane = threadIdx.x & 63;
    const int wv = threadIdx.x >> 6;
    const int bx = blockIdx.x;           // 0..1599
    const int tc = (bx & 1) << 6;
    const int g  = bx >> 1;
    const int sp = g % 50;
    const int b  = g / 50;
    const int s0 = sp * 2;
    const int t  = tc + lane;
    const int tcl = t < TGT ? t : TGT - 1;
    const int h0 = wv * 64;

    const float* __restrict__ ek0 = Ek + (size_t)(b * SRC + s0) * HH + h0;
    const float* __restrict__ ek1 = ek0 + HH;
    const float* __restrict__ eq  = EqT + (size_t)h0 * ROWS + (size_t)b * TGT + tcl;

    float acc0 = 0.f, acc1 = 0.f;
    #pragma unroll 4
    for (int hp = 0; hp < 32; ++hp) {
        const int h = hp * 2;
        const float w0 = W2[h0 + h], w1 = W2[h0 + h + 1];   // wave-uniform
        const float e0 = eq[(size_t)h * ROWS];
        const float e1 = eq[(size_t)(h + 1) * ROWS];
        const float ka0 = ek0[h], ka1 = ek0[h + 1];          // wave-uniform
        const float kb0 = ek1[h], kb1 = ek1[h + 1];
        acc0 = fmaf(w0, __builtin_amdgcn_rcpf(fmaf(ka0, e0, 1.0f)), acc0);
        acc1 = fmaf(w0, __builtin_amdgcn_rcpf(fmaf(kb0, e0, 1.0f)), acc1);
        acc0 = fmaf(w1, __builtin_amdgcn_rcpf(fmaf(ka1, e1, 1.0f)), acc0);
        acc1 = fmaf(w1, __builtin_amdgcn_rcpf(fmaf(kb1, e1, 1.0f)), acc1);
    }
    red[0][wv][lane] = acc0;
    red[1][wv][lane] = acc1;
    __syncthreads();

    if (wv < 2) {   // wave wv emits output row s0+wv at column t
        float a = red[wv][0][lane] + red[wv][1][lane] + red[wv][2][lane] + red[wv][3][lane];
        float sw = W2[lane] + W2[lane + 64] + W2[lane + 128] + W2[lane + 192];
        #pragma unroll
        for (int off = 32; off; off >>= 1) sw += __shfl_xor(sw, off, 64);
        const float x = sw - 2.f * a + B2[0];
        const float gx = __builtin_amdgcn_exp2f(LOG2E2 * x);
        if (t < TGT)
            out[((size_t)b * SRC + s0 + wv) * TGT + t] =
                1.f - 2.f * __builtin_amdgcn_rcpf(gx + 1.f);
    }
}

extern "C" void kernel_launch(void* const* d_in, const int* in_sizes, int n_in,
                              void* d_out, int out_size, void* d_ws, size_t ws_size,
                              hipStream_t stream) {
    const float* query = (const float*)d_in[0];
    const float* keys  = (const float*)d_in[1];
    const float* Wk    = (const float*)d_in[2];
    const float* Wq    = (const float*)d_in[3];
    const float* b1    = (const float*)d_in[4];
    const float* W2    = (const float*)d_in[5];
    const float* B2    = (const float*)d_in[6];
    float* out = (float*)d_out;

    float* Ek  = (float*)d_ws;
    float* EqT = Ek + EQT_OFF;
    short* Apk = (short*)(Ek + PK_FLOAT_OFF);
    short* Bpk = Apk + APK_SHORTS;

    prep_kernel<<<928, 256, 0, stream>>>(query, keys, Wk, Wq, Apk, Bpk);
    gemm_exp_kernel<<<800, 256, 0, stream>>>(Apk, Bpk, b1, Ek, EqT);
    score_kernel<<<1600, 256, 0, stream>>>(Ek, EqT, W2, B2, out);
}

// Round 5
// 92.752 us; speedup vs baseline: 1.1337x; 1.0110x over previous
//
#include <hip/hip_runtime.h>

#define TGT 100
#define SRC 100
#define KDIM 512
#define HH 256
#define ROWS 1600              // BS*100
#define LOG2E2 2.8853900817779268f   // 2/ln(2): e^(2x) = 2^(LOG2E2*x)

typedef __attribute__((ext_vector_type(8))) short bf16x8;
typedef __attribute__((ext_vector_type(4))) float f32x4;

// ws layout: floats [Ek 409600][EqT 409600] then shorts [Apk 1638400][Bpk 262144]
#define EQT_OFF 409600
#define PK_FLOAT_OFF 819200
#define APK_SHORTS 1638400     // 2 mats * 100 rt * 16 kk * 64 lane * 8

static __device__ __forceinline__ short f2b(float f) {
    union { float f; unsigned u; } v; v.f = f;
    return (short)((v.u + 0x7FFFu + ((v.u >> 16) & 1u)) >> 16);
}

// ---------------------------------------------------------------------------
// Prep: one-shot fp32->bf16 conversion into MFMA-fragment-contiguous layouts.
// Apk[(mat*100+rt)*16+kk][lane][8] : A[m=lane&15][k=kk*32+(lane>>4)*8+j]
// Bpk[(mat*16+ht)*16+kk][lane][8]  : W[k=kk*32+(lane>>4)*8+j][ht*16+(lane&15)]
// Pays the strided W gather + cvt ONCE.
// ---------------------------------------------------------------------------
__global__ __launch_bounds__(256) void prep_kernel(
    const float* __restrict__ query, const float* __restrict__ keys,
    const float* __restrict__ Wk, const float* __restrict__ Wq,
    short* __restrict__ Apk, short* __restrict__ Bpk)
{
    const int tid = blockIdx.x * 256 + threadIdx.x;
    if (tid < 204800) {                       // A-pack: (mat,rt,kk,lane)
        const int lane = tid & 63;
        const int rest = tid >> 6;            // (mat*100+rt)*16 + kk
        const int kk = rest & 15;
        const int rg = rest >> 4;             // mat*100+rt, 0..199
        const float* A = (rg >= 100) ? query : keys;
        const int r = (rg % 100) * 16 + (lane & 15);
        const int kb = kk * 32 + (lane >> 4) * 8;
        const float* src = A + (size_t)r * KDIM + kb;
        f32x4 a0 = *(const f32x4*)src;
        f32x4 a1 = *(const f32x4*)(src + 4);
        bf16x8 v;
        #pragma unroll
        for (int j = 0; j < 4; ++j) { v[j] = f2b(a0[j]); v[j + 4] = f2b(a1[j]); }
        *(bf16x8*)(Apk + (size_t)tid * 8) = v;
    } else if (tid < 237568) {                // B-pack: (mat,ht,kk,lane)
        const int t2 = tid - 204800;
        const int lane = t2 & 63;
        const int rest = t2 >> 6;             // (mat*16+ht)*16 + kk
        const int kk = rest & 15;
        const int ht = (rest >> 4) & 15;
        const float* W = (rest >> 8) ? Wq : Wk;
        const int kb = kk * 32 + (lane >> 4) * 8;
        const int col = ht * 16 + (lane & 15);
        const float* wp = W + (size_t)kb * HH + col;
        bf16x8 v;
        #pragma unroll
        for (int j = 0; j < 8; ++j) v[j] = f2b(wp[(size_t)j * HH]);
        *(bf16x8*)(Bpk + (size_t)t2 * 8) = v;
    }
}

// ---------------------------------------------------------------------------
// GEMM+exp: 1 wave per 16x16 C-tile, 4 waves/block (same rt per block -> L1
// reuse of the A stream). Inner loop = 2 contiguous 1KB bf16x8 loads + MFMA.
//   rt 0..99   : Ek [b*100+s][h]  = exp2(L * keys@Wk)
//   rt 100..199: EqT[h][b*100+t]  = exp2(L * (query@Wq + b1))  (transposed)
// D layout: col=lane&15, row=(lane>>4)*4+reg  (m89/m92-verified).
// ---------------------------------------------------------------------------
__global__ __launch_bounds__(256) void gemm_exp_kernel(
    const short* __restrict__ Apk, const short* __restrict__ Bpk,
    const float* __restrict__ b1,
    float* __restrict__ Ek, float* __restrict__ EqT)
{
    const int lane = threadIdx.x & 63;
    const int w = blockIdx.x * 4 + (threadIdx.x >> 6);   // 0..3199
    const int rt = w >> 4;               // 0..199 == mat*100 + rtl
    const int ht = w & 15;
    const int isq = rt >= 100;
    const short* ap = Apk + ((size_t)(rt * 16) * 64 + lane) * 8;
    const short* bp = Bpk + ((size_t)((isq * 16 + ht) * 16) * 64 + lane) * 8;

    f32x4 acc = {0.f, 0.f, 0.f, 0.f};
    #pragma unroll
    for (int kk = 0; kk < 16; ++kk) {
        bf16x8 af = *(const bf16x8*)(ap + (size_t)kk * 512);
        bf16x8 bf = *(const bf16x8*)(bp + (size_t)kk * 512);
        acc = __builtin_amdgcn_mfma_f32_16x16x32_bf16(af, bf, acc, 0, 0, 0);
    }

    const int m = lane & 15, q = lane >> 4;
    const int hc = ht * 16 + m;
    const int r0 = (isq ? rt - 100 : rt) * 16;
    if (!isq) {
        #pragma unroll
        for (int r = 0; r < 4; ++r) {
            const int row = r0 + q * 4 + r;
            Ek[(size_t)row * HH + hc] = __builtin_amdgcn_exp2f(LOG2E2 * acc[r]);
        }
    } else {
        const float bb = b1[hc];
        #pragma unroll
        for (int r = 0; r < 4; ++r) {
            const int row = r0 + q * 4 + r;
            EqT[(size_t)hc * ROWS + row] =
                __builtin_amdgcn_exp2f(LOG2E2 * (acc[r] + bb));
        }
    }
}

// ---------------------------------------------------------------------------
// Score: score[b][s][t] = tanh(sumW2 - 2*sum_h W2[h]/(Ek[s,h]*Eq[t,h]+1) + b2)
// Block (256 thr) = (b, s-QUAD, 64-t-chunk); each of 4 waves takes a 64-h
// quarter for all 4 s. Per iter: 7 loads (float2 ek x4, eq x2, W2 float2)
// covering 512 (s,t,h) elems -> 2.3x fewer vmem instrs than s-pair version.
// 4KB LDS reduce; wave w emits output row s0+w. grid = 16*25*2 = 800 blocks.
// ---------------------------------------------------------------------------
__global__ __launch_bounds__(256) void score_kernel(
    const float* __restrict__ Ek, const float* __restrict__ EqT,
    const float* __restrict__ W2, const float* __restrict__ B2,
    float* __restrict__ out)
{
    __shared__ float red[4][4][64];
    const int lane = threadIdx.x & 63;
    const int wv = threadIdx.x >> 6;
    const int bx = blockIdx.x;           // 0..799
    const int tc = (bx & 1) << 6;        // 0 or 64
    const int g  = bx >> 1;              // 0..399
    const int sq = g % 25;
    const int b  = g / 25;
    const int s0 = sq * 4;
    const int t  = tc + lane;
    const int tcl = t < TGT ? t : TGT - 1;
    const int h0 = wv * 64;

    const float* __restrict__ ek = Ek + (size_t)(b * SRC + s0) * HH + h0;
    const float* __restrict__ eq = EqT + (size_t)h0 * ROWS + (size_t)b * TGT + tcl;
    const float* __restrict__ w2 = W2 + h0;

    float acc0 = 0.f, acc1 = 0.f, acc2 = 0.f, acc3 = 0.f;
    #pragma unroll 4
    for (int hp = 0; hp < 32; ++hp) {
        const int h = hp * 2;
        const float2 w  = *(const float2*)(w2 + h);
        const float  e0 = eq[(size_t)h * ROWS];
        const float  e1 = eq[(size_t)(h + 1) * ROWS];
        const float2 k0 = *(const float2*)(ek + h);
        const float2 k1 = *(const float2*)(ek + HH + h);
        const float2 k2 = *(const float2*)(ek + 2 * HH + h);
        const float2 k3 = *(const float2*)(ek + 3 * HH + h);
        acc0 = fmaf(w.x, __builtin_amdgcn_rcpf(fmaf(k0.x, e0, 1.f)), acc0);
        acc1 = fmaf(w.x, __builtin_amdgcn_rcpf(fmaf(k1.x, e0, 1.f)), acc1);
        acc2 = fmaf(w.x, __builtin_amdgcn_rcpf(fmaf(k2.x, e0, 1.f)), acc2);
        acc3 = fmaf(w.x, __builtin_amdgcn_rcpf(fmaf(k3.x, e0, 1.f)), acc3);
        acc0 = fmaf(w.y, __builtin_amdgcn_rcpf(fmaf(k0.y, e1, 1.f)), acc0);
        acc1 = fmaf(w.y, __builtin_amdgcn_rcpf(fmaf(k1.y, e1, 1.f)), acc1);
        acc2 = fmaf(w.y, __builtin_amdgcn_rcpf(fmaf(k2.y, e1, 1.f)), acc2);
        acc3 = fmaf(w.y, __builtin_amdgcn_rcpf(fmaf(k3.y, e1, 1.f)), acc3);
    }
    red[0][wv][lane] = acc0;
    red[1][wv][lane] = acc1;
    red[2][wv][lane] = acc2;
    red[3][wv][lane] = acc3;
    __syncthreads();

    // wave wv emits output row s0+wv at column t
    float a = red[wv][0][lane] + red[wv][1][lane] + red[wv][2][lane] + red[wv][3][lane];
    float sw = W2[lane] + W2[lane + 64] + W2[lane + 128] + W2[lane + 192];
    #pragma unroll
    for (int off = 32; off; off >>= 1) sw += __shfl_xor(sw, off, 64);
    const float x = sw - 2.f * a + B2[0];
    const float gx = __builtin_amdgcn_exp2f(LOG2E2 * x);
    if (t < TGT)
        out[((size_t)b * SRC + s0 + wv) * TGT + t] =
            1.f - 2.f * __builtin_amdgcn_rcpf(gx + 1.f);
}

extern "C" void kernel_launch(void* const* d_in, const int* in_sizes, int n_in,
                              void* d_out, int out_size, void* d_ws, size_t ws_size,
                              hipStream_t stream) {
    const float* query = (const float*)d_in[0];
    const float* keys  = (const float*)d_in[1];
    const float* Wk    = (const float*)d_in[2];
    const float* Wq    = (const float*)d_in[3];
    const float* b1    = (const float*)d_in[4];
    const float* W2    = (const float*)d_in[5];
    const float* B2    = (const float*)d_in[6];
    float* out = (float*)d_out;

    float* Ek  = (float*)d_ws;
    float* EqT = Ek + EQT_OFF;
    short* Apk = (short*)(Ek + PK_FLOAT_OFF);
    short* Bpk = Apk + APK_SHORTS;

    prep_kernel<<<928, 256, 0, stream>>>(query, keys, Wk, Wq, Apk, Bpk);
    gemm_exp_kernel<<<800, 256, 0, stream>>>(Apk, Bpk, b1, Ek, EqT);
    score_kernel<<<800, 256, 0, stream>>>(Ek, EqT, W2, B2, out);
}